// Round 5
// baseline (194.513 us; speedup 1.0000x reference)
//
#include <hip/hip_runtime.h>
#include <math.h>

#define EPS_F 1e-6f
#define NCH   8          // KV chunks
#define CHUNK 1024       // 8192 / NCH
#define TILES 32         // CHUNK / 32
#define QSC   (0.125f * 1.44269504088896340736f)   // ATTN_SCALE * log2(e)

typedef __attribute__((ext_vector_type(8))) short short8;
typedef __attribute__((ext_vector_type(4))) float f32x4;
typedef unsigned short ushort_t;
typedef unsigned int uint_t;

__device__ __forceinline__ ushort_t f2bf(float x){
  uint_t u = __float_as_uint(x);
  u += 0x7fffu + ((u >> 16) & 1u);
  return (ushort_t)(u >> 16);
}
__device__ __forceinline__ float bf2f(ushort_t u){
  return __uint_as_float(((uint_t)u) << 16);
}
__device__ __forceinline__ uint_t pack2bf(float lo, float hi){
  return (uint_t)f2bf(lo) | ((uint_t)f2bf(hi) << 16);
}

__device__ __forceinline__ float wave_sum64(float v){
  #pragma unroll
  for (int m = 32; m > 0; m >>= 1) v += __shfl_xor(v, m, 64);
  return v;
}
__device__ __forceinline__ float qsum16(float v){
  #pragma unroll
  for (int m = 1; m < 16; m <<= 1) v += __shfl_xor(v, m, 64);
  return v;
}

__device__ __forceinline__ short8 neg8(short8 v){
  uint4 u = *reinterpret_cast<uint4*>(&v);
  u.x ^= 0x80008000u; u.y ^= 0x80008000u; u.z ^= 0x80008000u; u.w ^= 0x80008000u;
  return *reinterpret_cast<short8*>(&u);
}

// load 8 consecutive fp32, split into bf16 hi + lo fragments
__device__ __forceinline__ void wsplit(const float* __restrict__ p, short8& hi, short8& lo){
  float4 a = *reinterpret_cast<const float4*>(p);
  float4 b = *reinterpret_cast<const float4*>(p + 4);
  float f[8] = {a.x, a.y, a.z, a.w, b.x, b.y, b.z, b.w};
  #pragma unroll
  for (int e = 0; e < 8; ++e){
    ushort_t h = f2bf(f[e]);
    hi[e] = (short)h;
    lo[e] = (short)f2bf(f[e] - bf2f(h));
  }
}
// load 8 consecutive fp32 as single bf16 fragment
__device__ __forceinline__ short8 wsingle(const float* __restrict__ p){
  float4 a = *reinterpret_cast<const float4*>(p);
  float4 b = *reinterpret_cast<const float4*>(p + 4);
  float f[8] = {a.x, a.y, a.z, a.w, b.x, b.y, b.z, b.w};
  short8 hi;
  #pragma unroll
  for (int e = 0; e < 8; ++e) hi[e] = (short)f2bf(f[e]);
  return hi;
}

#define MFMA(a,b,c) __builtin_amdgcn_mfma_f32_16x16x32_bf16((a),(b),(c),0,0,0)

// ============ prep v2: all projections on MFMA, 1 wave = 16 rows ============
__global__ __launch_bounds__(64) void prep_kernel(
    const float* __restrict__ z_real, const float* __restrict__ z_imag,
    const float* __restrict__ gate_W, const float* __restrict__ gate_b,
    const float* __restrict__ exp_Wr, const float* __restrict__ exp_Wi,
    const float* __restrict__ ln_scale, const float* __restrict__ ln_shift,
    const float* __restrict__ mod_bias,
    const float* __restrict__ q_Wr, const float* __restrict__ q_Wi,
    const float* __restrict__ k_Wr, const float* __restrict__ k_Wi,
    const float* __restrict__ v_Wr, const float* __restrict__ v_Wi,
    const float* __restrict__ ctx_W, const float* __restrict__ ctx_b,
    const float* __restrict__ res_W, const float* __restrict__ res_b,
    ushort_t* __restrict__ qf, ushort_t* __restrict__ kf, ushort_t* __restrict__ vt,
    float* __restrict__ resb)
{
  const int lane = threadIdx.x;
  const int g    = lane >> 4;        // 0..3
  const int c    = lane & 15;        // 0..15 (A-frag row / C-frag col)
  const int row0 = blockIdx.x * 16;
  const f32x4 z4 = {0.f, 0.f, 0.f, 0.f};

  __shared__ ushort_t s_xh[16][136];   // zf hi  [row][0..63 re | 64..127 im]
  __shared__ ushort_t s_xl[16][136];   // zf lo
  __shared__ ushort_t s_a [16][136];   // ar|ai bf16 (post LN+ModReLU)
  __shared__ ushort_t s_tv[128][20];   // V^T staging

  // ---- stage zf as hi/lo bf16 ----
  {
    int rowl = lane >> 2, seg = lane & 3;
    const float* pr = z_real + (size_t)(row0 + rowl) * 64 + seg * 16;
    const float* pi = z_imag + (size_t)(row0 + rowl) * 64 + seg * 16;
    #pragma unroll
    for (int half = 0; half < 2; ++half){
      const float* src = half ? pi : pr;
      int base = half * 64 + seg * 16;
      #pragma unroll
      for (int jj = 0; jj < 4; ++jj){
        float4 v = *reinterpret_cast<const float4*>(src + jj * 4);
        float f[4] = {v.x, v.y, v.z, v.w};
        uint_t h0, h1, l0, l1;
        ushort_t ha = f2bf(f[0]), hb = f2bf(f[1]), hc2 = f2bf(f[2]), hd = f2bf(f[3]);
        h0 = (uint_t)ha | ((uint_t)hb << 16);
        h1 = (uint_t)hc2 | ((uint_t)hd << 16);
        l0 = (uint_t)f2bf(f[0] - bf2f(ha)) | ((uint_t)f2bf(f[1] - bf2f(hb)) << 16);
        l1 = (uint_t)f2bf(f[2] - bf2f(hc2)) | ((uint_t)f2bf(f[3] - bf2f(hd)) << 16);
        uint2 uh; uh.x = h0; uh.y = h1;
        uint2 ul; ul.x = l0; ul.y = l1;
        *reinterpret_cast<uint2*>(&s_xh[rowl][base + jj * 4]) = uh;
        *reinterpret_cast<uint2*>(&s_xl[rowl][base + jj * 4]) = ul;
      }
    }
  }
  __syncthreads();

  // x fragments (zf): [ks] over K=128
  short8 xh[4], xl[4];
  #pragma unroll
  for (int ks = 0; ks < 4; ++ks){
    xh[ks] = *reinterpret_cast<const short8*>(&s_xh[c][ks * 32 + g * 8]);
    xl[ks] = *reinterpret_cast<const short8*>(&s_xl[c][ks * 32 + g * 8]);
  }

  // ---- gate (compensated): logits C-frag col=e(c), rows 4g+r ----
  float gwv[4];
  {
    f32x4 ga = z4;
    #pragma unroll
    for (int ks = 0; ks < 4; ++ks){
      short8 wh, wl;
      wsplit(gate_W + (c & 3) * 128 + ks * 32 + g * 8, wh, wl);
      ga = MFMA(xh[ks], wh, ga);
      ga = MFMA(xl[ks], wh, ga);
      ga = MFMA(xh[ks], wl, ga);
    }
    float gb = gate_b[c & 3];
    float le[4];
    #pragma unroll
    for (int r = 0; r < 4; ++r) le[r] = ga[r] + gb;
    #pragma unroll
    for (int r = 0; r < 4; ++r){
      float mx = fmaxf(le[r], __shfl_xor(le[r], 1, 64));
      mx = fmaxf(mx, __shfl_xor(mx, 2, 64));
      float ev = __expf(le[r] - mx);
      float sm = ev + __shfl_xor(ev, 1, 64);
      sm += __shfl_xor(sm, 2, 64);
      gwv[r] = ev / sm;
    }
  }

  // ---- MoE (fully compensated): m = sum_e gw[e] * (z @ We^T) ----
  f32x4 mrr[4], mri[4];
  #pragma unroll
  for (int ct = 0; ct < 4; ++ct){ mrr[ct] = z4; mri[ct] = z4; }

  for (int e = 0; e < 4; ++e){
    float gwr[4];
    #pragma unroll
    for (int r = 0; r < 4; ++r) gwr[r] = __shfl(gwv[r], g * 16 + e, 64);
    const float* bWr = exp_Wr + e * 4096 + c * 64 + g * 8;
    const float* bWi = exp_Wi + e * 4096 + c * 64 + g * 8;
    #pragma unroll
    for (int ct = 0; ct < 4; ++ct){
      f32x4 er = z4, ei = z4;
      #pragma unroll
      for (int ks = 0; ks < 2; ++ks){
        short8 wrh, wrl, wih, wil;
        wsplit(bWr + ct * 1024 + ks * 32, wrh, wrl);
        wsplit(bWi + ct * 1024 + ks * 32, wih, wil);
        short8 wihn = neg8(wih), wiln = neg8(wil);
        // xr = xh[ks], xi = xh[ks+2] (cols 64..127)
        er = MFMA(xh[ks],   wrh, er);  ei = MFMA(xh[ks+2], wrh, ei);
        er = MFMA(xl[ks],   wrh, er);  ei = MFMA(xl[ks+2], wrh, ei);
        er = MFMA(xh[ks],   wrl, er);  ei = MFMA(xh[ks+2], wrl, ei);
        er = MFMA(xh[ks+2], wihn, er); ei = MFMA(xh[ks],   wih, ei);
        er = MFMA(xl[ks+2], wihn, er); ei = MFMA(xl[ks],   wih, ei);
        er = MFMA(xh[ks+2], wiln, er); ei = MFMA(xh[ks],   wil, ei);
      }
      #pragma unroll
      for (int r = 0; r < 4; ++r){
        mrr[ct][r] = fmaf(gwr[r], er[r], mrr[ct][r]);
        mri[ct][r] = fmaf(gwr[r], ei[r], mri[ct][r]);
      }
    }
  }

  // ---- ComplexLayerNorm (ddof=1) + ModReLU -> s_a (bf16) ----
  {
    float lsc[4], lsh[4], mb[4];
    #pragma unroll
    for (int ct = 0; ct < 4; ++ct){
      lsc[ct] = ln_scale[ct * 16 + c];
      lsh[ct] = ln_shift[ct * 16 + c];
      mb[ct]  = mod_bias[ct * 16 + c];
    }
    #pragma unroll
    for (int r = 0; r < 4; ++r){
      float hh[4], mg[4], sum = 0.f;
      #pragma unroll
      for (int ct = 0; ct < 4; ++ct){
        hh[ct] = sqrtf(mrr[ct][r] * mrr[ct][r] + mri[ct][r] * mri[ct][r]);
        mg[ct] = hh[ct] + EPS_F;
        sum += mg[ct];
      }
      float mean = qsum16(sum) * (1.0f / 64.0f);
      float s2 = 0.f;
      #pragma unroll
      for (int ct = 0; ct < 4; ++ct){ float d = mg[ct] - mean; s2 += d * d; }
      float istd = rsqrtf(qsum16(s2) * (1.0f / 63.0f) + EPS_F);
      #pragma unroll
      for (int ct = 0; ct < 4; ++ct){
        float nm = (mg[ct] - mean) * istd * lsc[ct] + lsh[ct];
        float lr, li;
        if (hh[ct] > 0.f){ float ih = 1.0f / hh[ct]; lr = nm * mrr[ct][r] * ih; li = nm * mri[ct][r] * ih; }
        else             { lr = nm; li = 0.f; }
        float nrm = sqrtf(lr * lr + li * li) + EPS_F;
        float sf  = fmaxf(nrm + mb[ct], 0.f) / nrm;
        s_a[4 * g + r][ct * 16 + c]      = f2bf(lr * sf);
        s_a[4 * g + r][64 + ct * 16 + c] = f2bf(li * sf);
      }
    }
  }
  __syncthreads();

  // ---- ctx gate (single bf16): cw = sigmoid(zf @ ctx_W^T + b) ----
  f32x4 cwa[8];
  #pragma unroll
  for (int ct8 = 0; ct8 < 8; ++ct8){
    f32x4 a = z4;
    #pragma unroll
    for (int ks = 0; ks < 4; ++ks){
      short8 wh = wsingle(ctx_W + (ct8 * 16 + c) * 128 + ks * 32 + g * 8);
      a = MFMA(xh[ks], wh, a);
    }
    float cb = ctx_b[ct8 * 16 + c];
    #pragma unroll
    for (int r = 0; r < 4; ++r) cwa[ct8][r] = 1.0f / (1.0f + __expf(-(a[r] + cb)));
  }

  // ---- residual (single bf16): resb = 0.1*(zf @ res_W^T + b), fp32 out ----
  #pragma unroll
  for (int ct8 = 0; ct8 < 8; ++ct8){
    f32x4 a = z4;
    #pragma unroll
    for (int ks = 0; ks < 4; ++ks){
      short8 wh = wsingle(res_W + (ct8 * 16 + c) * 128 + ks * 32 + g * 8);
      a = MFMA(xh[ks], wh, a);
    }
    float rb = res_b[ct8 * 16 + c];
    #pragma unroll
    for (int r = 0; r < 4; ++r)
      resb[(size_t)(row0 + 4 * g + r) * 128 + ct8 * 16 + c] = 0.1f * (a[r] + rb);
  }

  // ---- QKV (a single bf16, W compensated) ----
  short8 ar_[2], ai_[2], ain_[2];
  #pragma unroll
  for (int ks = 0; ks < 2; ++ks){
    ar_[ks]  = *reinterpret_cast<const short8*>(&s_a[c][ks * 32 + g * 8]);
    ai_[ks]  = *reinterpret_cast<const short8*>(&s_a[c][64 + ks * 32 + g * 8]);
    ain_[ks] = neg8(ai_[ks]);
  }

  #pragma unroll
  for (int mat = 0; mat < 3; ++mat){
    const float* Wr = (mat == 0) ? q_Wr : (mat == 1) ? k_Wr : v_Wr;
    const float* Wi = (mat == 0) ? q_Wi : (mat == 1) ? k_Wi : v_Wi;
    #pragma unroll
    for (int ct = 0; ct < 4; ++ct){
      f32x4 orr = z4, oii = z4;
      #pragma unroll
      for (int ks = 0; ks < 2; ++ks){
        short8 wrh, wrl, wih, wil;
        wsplit(Wr + (ct * 16 + c) * 64 + ks * 32 + g * 8, wrh, wrl);
        wsplit(Wi + (ct * 16 + c) * 64 + ks * 32 + g * 8, wih, wil);
        orr = MFMA(ar_[ks],  wrh, orr);  oii = MFMA(ai_[ks], wrh, oii);
        orr = MFMA(ar_[ks],  wrl, orr);  oii = MFMA(ai_[ks], wrl, oii);
        orr = MFMA(ain_[ks], wih, orr);  oii = MFMA(ar_[ks], wih, oii);
        orr = MFMA(ain_[ks], wil, orr);  oii = MFMA(ar_[ks], wil, oii);
      }
      if (mat == 0){        // Q: gate + fold scale*log2e
        #pragma unroll
        for (int r = 0; r < 4; ++r){
          size_t row = row0 + 4 * g + r;
          qf[row * 128 + ct * 16 + c]      = f2bf(orr[r] * cwa[ct][r]     * QSC);
          qf[row * 128 + 64 + ct * 16 + c] = f2bf(oii[r] * cwa[ct + 4][r] * QSC);
        }
      } else if (mat == 1){ // K
        #pragma unroll
        for (int r = 0; r < 4; ++r){
          size_t row = row0 + 4 * g + r;
          kf[row * 128 + ct * 16 + c]      = f2bf(orr[r]);
          kf[row * 128 + 64 + ct * 16 + c] = f2bf(oii[r]);
        }
      } else {              // V -> LDS transpose staging
        #pragma unroll
        for (int r = 0; r < 4; ++r){
          s_tv[ct * 16 + c][4 * g + r]      = f2bf(orr[r]);
          s_tv[64 + ct * 16 + c][4 * g + r] = f2bf(oii[r]);
        }
      }
    }
  }
  __syncthreads();

  // ---- V^T write-out: vt[d][8192] ----
  #pragma unroll
  for (int p = 0; p < 2; ++p){
    int d = p * 64 + lane;
    uint2 t0 = *reinterpret_cast<const uint2*>(&s_tv[d][0]);
    uint2 t1 = *reinterpret_cast<const uint2*>(&s_tv[d][4]);
    uint2 t2 = *reinterpret_cast<const uint2*>(&s_tv[d][8]);
    uint2 t3 = *reinterpret_cast<const uint2*>(&s_tv[d][12]);
    uint4 o0; o0.x = t0.x; o0.y = t0.y; o0.z = t1.x; o0.w = t1.y;
    uint4 o1; o1.x = t2.x; o1.y = t2.y; o1.z = t3.x; o1.w = t3.y;
    *reinterpret_cast<uint4*>(vt + (size_t)d * 8192 + row0)     = o0;
    *reinterpret_cast<uint4*>(vt + (size_t)d * 8192 + row0 + 8) = o1;
  }
}

// ---- MFMA flash attention (swapped operands, exp2 domain, defer-max) ----
__global__ __launch_bounds__(256, 4) void attn_mfma(
    const ushort_t* __restrict__ qf, const ushort_t* __restrict__ kf, const ushort_t* __restrict__ vt,
    ushort_t* __restrict__ pacc, float* __restrict__ pm, float* __restrict__ pl)
{
  const int tid  = threadIdx.x;
  const int lane = tid & 63;
  const int w    = tid >> 6;
  const int g    = lane >> 4;
  const int hl   = lane & 15;
  const int qb   = blockIdx.x & 127;
  const int jc   = blockIdx.x >> 7;
  const int q0   = qb * 64;
  const int qr   = q0 + w * 16 + hl;

  __shared__ ushort_t s_k[32][136];
  __shared__ ushort_t s_vt[128][40];
  __shared__ uint_t   s_p32[4][16][20];

  const int kjj0 = tid >> 4;
  const int kkk  = (tid & 15) * 8;
  const int vd0  = tid >> 2;
  const int vjo  = (tid & 3) * 8;

  short8 qfrag[4];
  #pragma unroll
  for (int kt = 0; kt < 4; ++kt)
    qfrag[kt] = *reinterpret_cast<const short8*>(qf + (size_t)qr * 128 + kt * 32 + g * 8);

  f32x4 oacc[8];
  #pragma unroll
  for (int dt = 0; dt < 8; ++dt) oacc[dt] = (f32x4){0.f, 0.f, 0.f, 0.f};
  float mrun = -3.0e38f, lrun = 0.f;

  const int jstart = jc * CHUNK;

  for (int t = 0; t < TILES; ++t){
    const int jb = jstart + t * 32;
    __syncthreads();
    #pragma unroll
    for (int i = 0; i < 2; ++i){
      *reinterpret_cast<uint4*>(&s_k[kjj0 + i * 16][kkk]) =
          *reinterpret_cast<const uint4*>(kf + (size_t)(jb + kjj0 + i * 16) * 128 + kkk);
      *reinterpret_cast<uint4*>(&s_vt[vd0 + i * 64][vjo]) =
          *reinterpret_cast<const uint4*>(vt + (size_t)(vd0 + i * 64) * 8192 + jb + vjo);
    }
    __syncthreads();

    f32x4 sacc[2];
    #pragma unroll
    for (int jt = 0; jt < 2; ++jt){
      sacc[jt] = (f32x4){0.f, 0.f, 0.f, 0.f};
      #pragma unroll
      for (int kt = 0; kt < 4; ++kt){
        short8 kfr = *reinterpret_cast<const short8*>(&s_k[jt * 16 + hl][kt * 32 + g * 8]);
        sacc[jt] = __builtin_amdgcn_mfma_f32_16x16x32_bf16(kfr, qfrag[kt], sacc[jt], 0, 0, 0);
      }
    }

    // per-lane online softmax in exp2 domain, defer-max
    float t0 = fmaxf(fmaxf(fmaxf(sacc[0][0], sacc[0][1]), fmaxf(sacc[0][2], sacc[0][3])),
                     fmaxf(fmaxf(sacc[1][0], sacc[1][1]), fmaxf(sacc[1][2], sacc[1][3])));
    t0 = fmaxf(t0, __shfl_xor(t0, 16, 64));
    t0 = fmaxf(t0, __shfl_xor(t0, 32, 64));
    if (__any(t0 > mrun)){
      float mnew = fmaxf(mrun, t0);
      float fac  = exp2f(mrun - mnew);
      lrun *= fac;
      #pragma unroll
      for (int dt = 0; dt < 8; ++dt){
        oacc[dt][0] *= fac; oacc[dt][1] *= fac; oacc[dt][2] *= fac; oacc[dt][3] *= fac;
      }
      mrun = mnew;
    }
    float pe[2][4];
    float ps = 0.f;
    #pragma unroll
    for (int jt = 0; jt < 2; ++jt)
      #pragma unroll
      for (int r = 0; r < 4; ++r){
        float p = exp2f(sacc[jt][r] - mrun);
        pe[jt][r] = p;
        ps += p;
      }
    ps += __shfl_xor(ps, 16, 64);
    ps += __shfl_xor(ps, 32, 64);
    lrun += ps;

    {
      uint2 w0; w0.x = pack2bf(pe[0][0], pe[0][1]); w0.y = pack2bf(pe[0][2], pe[0][3]);
      uint2 w1; w1.x = pack2bf(pe[1][0], pe[1][1]); w1.y = pack2bf(pe[1][2], pe[1][3]);
      *reinterpret_cast<uint2*>(&s_p32[w][hl][2 * g])     = w0;
      *reinterpret_cast<uint2*>(&s_p32[w][hl][8 + 2 * g]) = w1;
    }
    short8 pfrag = *reinterpret_cast<const short8*>(&s_p32[w][hl][4 * g]);

    #pragma unroll
    for (int dt = 0; dt < 8; ++dt){
      short8 vfr = *reinterpret_cast<const short8*>(&s_vt[dt * 16 + hl][g * 8]);
      oacc[dt] = __builtin_amdgcn_mfma_f32_16x16x32_bf16(vfr, pfrag, oacc[dt], 0, 0, 0);
    }
  }

  #pragma unroll
  for (int dt = 0; dt < 8; ++dt){
    uint2 o;
    o.x = pack2bf(oacc[dt][0], oacc[dt][1]);
    o.y = pack2bf(oacc[dt][2], oacc[dt][3]);
    *reinterpret_cast<uint2*>(pacc + ((size_t)jc * 8192 + qr) * 128 + dt * 16 + 4 * g) = o;
  }
  if (g == 0){
    pm[jc * 8192 + qr] = mrun;
    pl[jc * 8192 + qr] = lrun;
  }
}

// ---- combine chunk partials + residual + halt/stack heads ----
__global__ __launch_bounds__(256, 1) void combine_kernel(
    const ushort_t* __restrict__ pacc, const float* __restrict__ pm, const float* __restrict__ pl,
    const float* __restrict__ resb,
    const float* __restrict__ halt_W, const float* __restrict__ halt_b,
    const float* __restrict__ stack_W, const float* __restrict__ stack_b,
    float* __restrict__ out)
{
  const int tid  = threadIdx.x;
  const int lane = tid & 63;
  const int w    = tid >> 6;
  const int q    = blockIdx.x * 4 + w;

  float mv[NCH], M = -3.0e38f;
  #pragma unroll
  for (int c = 0; c < NCH; ++c){ mv[c] = pm[c * 8192 + q]; M = fmaxf(M, mv[c]); }
  float f[NCH]; float L = 0.f;
  #pragma unroll
  for (int c = 0; c < NCH; ++c){ f[c] = exp2f(mv[c] - M); L += pl[c * 8192 + q] * f[c]; }
  float invL = 1.0f / L;

  float o0 = 0.f, o1 = 0.f;
  #pragma unroll
  for (int c = 0; c < NCH; ++c){
    const ushort_t* pa = pacc + ((size_t)c * 8192 + q) * 128;
    o0 += bf2f(pa[lane])      * f[c];
    o1 += bf2f(pa[64 + lane]) * f[c];
  }
  o0 = o0 * invL + resb[(size_t)q * 128 + lane];
  o1 = o1 * invL + resb[(size_t)q * 128 + 64 + lane];
  out[(size_t)q * 64 + lane] = o0;
  out[(size_t)8192 * 64 + (size_t)q * 64 + lane] = o1;

  float ssq  = wave_sum64(o0 * o0 + o1 * o1);
  float invn = 1.0f / (sqrtf(ssq) + 1e-6f);
  float zn0 = o0 * invn, zn1 = o1 * invn;
  float hp = wave_sum64(zn0 * halt_W[lane]        + zn1 * halt_W[64 + lane]);
  float s0 = wave_sum64(zn0 * stack_W[lane]       + zn1 * stack_W[64 + lane]);
  float s1 = wave_sum64(zn0 * stack_W[128 + lane] + zn1 * stack_W[192 + lane]);
  float s2 = wave_sum64(zn0 * stack_W[256 + lane] + zn1 * stack_W[320 + lane]);
  if (lane == 0){
    out[1048576 + q] = hp + halt_b[0];
    out[1056768 + (size_t)q * 3 + 0] = s0 + stack_b[0];
    out[1056768 + (size_t)q * 3 + 1] = s1 + stack_b[1];
    out[1056768 + (size_t)q * 3 + 2] = s2 + stack_b[2];
  }
}

extern "C" void kernel_launch(void* const* d_in, const int* in_sizes, int n_in,
                              void* d_out, int out_size, void* d_ws, size_t ws_size,
                              hipStream_t stream){
  const float* z_real  = (const float*)d_in[0];
  const float* z_imag  = (const float*)d_in[1];
  const float* gate_W  = (const float*)d_in[2];
  const float* gate_b  = (const float*)d_in[3];
  const float* exp_Wr  = (const float*)d_in[4];
  const float* exp_Wi  = (const float*)d_in[5];
  const float* ln_scale= (const float*)d_in[6];
  const float* ln_shift= (const float*)d_in[7];
  const float* mod_bias= (const float*)d_in[8];
  const float* q_Wr    = (const float*)d_in[9];
  const float* q_Wi    = (const float*)d_in[10];
  const float* k_Wr    = (const float*)d_in[11];
  const float* k_Wi    = (const float*)d_in[12];
  const float* v_Wr    = (const float*)d_in[13];
  const float* v_Wi    = (const float*)d_in[14];
  const float* ctx_W   = (const float*)d_in[15];
  const float* ctx_b   = (const float*)d_in[16];
  const float* res_W   = (const float*)d_in[17];
  const float* res_b   = (const float*)d_in[18];
  const float* halt_W  = (const float*)d_in[19];
  const float* halt_b  = (const float*)d_in[20];
  const float* stack_W = (const float*)d_in[21];
  const float* stack_b = (const float*)d_in[22];

  ushort_t* qbf = (ushort_t*)d_ws;
  ushort_t* kbf = qbf + (size_t)8192*128;
  ushort_t* vtb = kbf + (size_t)8192*128;        // transposed V [128][8192]
  float* resb = (float*)(vtb + (size_t)8192*128);
  ushort_t* pacc = (ushort_t*)(resb + (size_t)8192*128);
  float* pm   = (float*)(pacc + (size_t)NCH*8192*128);
  float* pl   = pm   + NCH*8192;

  prep_kernel<<<512, 64, 0, stream>>>(z_real, z_imag, gate_W, gate_b, exp_Wr, exp_Wi,
      ln_scale, ln_shift, mod_bias, q_Wr, q_Wi, k_Wr, k_Wi, v_Wr, v_Wi,
      ctx_W, ctx_b, res_W, res_b, qbf, kbf, vtb, resb);
  attn_mfma<<<128*NCH, 256, 0, stream>>>(qbf, kbf, vtb, pacc, pm, pl);
  combine_kernel<<<2048, 256, 0, stream>>>(pacc, pm, pl, resb,
      halt_W, halt_b, stack_W, stack_b, (float*)d_out);
}

// Round 6
// 122.271 us; speedup vs baseline: 1.5908x; 1.5908x over previous
//
#include <hip/hip_runtime.h>
#include <math.h>

#define EPS_F 1e-6f
#define NCH   8          // KV chunks
#define CHUNK 1024       // 8192 / NCH
#define TILES 32         // CHUNK / 32
#define QSC   (0.125f * 1.44269504088896340736f)   // ATTN_SCALE * log2(e)

// weight-buffer offsets (elements) in whi/wlo
#define GATE_O 0
#define EWR_O  512
#define EWI_O  16896
#define QWR_O  33280
#define QWI_O  37376
#define KWR_O  41472
#define KWI_O  45568
#define VWR_O  49664
#define VWI_O  53760
#define CTX_O  57856
#define RES_O  74240
#define WTOT   90624

typedef __attribute__((ext_vector_type(8))) short short8;
typedef __attribute__((ext_vector_type(4))) float f32x4;
typedef unsigned short ushort_t;
typedef unsigned int uint_t;

__device__ __forceinline__ ushort_t f2bf(float x){
  uint_t u = __float_as_uint(x);
  u += 0x7fffu + ((u >> 16) & 1u);
  return (ushort_t)(u >> 16);
}
__device__ __forceinline__ float bf2f(ushort_t u){
  return __uint_as_float(((uint_t)u) << 16);
}
__device__ __forceinline__ uint_t pack2bf(float lo, float hi){
  return (uint_t)f2bf(lo) | ((uint_t)f2bf(hi) << 16);
}

__device__ __forceinline__ float wave_sum64(float v){
  #pragma unroll
  for (int m = 32; m > 0; m >>= 1) v += __shfl_xor(v, m, 64);
  return v;
}
__device__ __forceinline__ float qsum16(float v){
  #pragma unroll
  for (int m = 1; m < 16; m <<= 1) v += __shfl_xor(v, m, 64);
  return v;
}

__device__ __forceinline__ short8 neg8(short8 v){
  uint4 u = *reinterpret_cast<uint4*>(&v);
  u.x ^= 0x80008000u; u.y ^= 0x80008000u; u.z ^= 0x80008000u; u.w ^= 0x80008000u;
  return *reinterpret_cast<short8*>(&u);
}
__device__ __forceinline__ short8 ld8(const ushort_t* __restrict__ p){
  return *reinterpret_cast<const short8*>(p);
}

#define MFMA(a,b,c) __builtin_amdgcn_mfma_f32_16x16x32_bf16((a),(b),(c),0,0,0)

// ============ weight conversion: fp32 -> bf16 hi/lo, fragment-ready ============
__global__ __launch_bounds__(256) void wconv_kernel(
    const float* __restrict__ gate_W, const float* __restrict__ exp_Wr,
    const float* __restrict__ exp_Wi,
    const float* __restrict__ q_Wr, const float* __restrict__ q_Wi,
    const float* __restrict__ k_Wr, const float* __restrict__ k_Wi,
    const float* __restrict__ v_Wr, const float* __restrict__ v_Wi,
    const float* __restrict__ ctx_W, const float* __restrict__ res_W,
    ushort_t* __restrict__ whi, ushort_t* __restrict__ wlo)
{
  int i = blockIdx.x * 256 + threadIdx.x;
  if (i >= WTOT) return;
  float v;
  if      (i < EWR_O) v = gate_W[i - GATE_O];
  else if (i < EWI_O) v = exp_Wr[i - EWR_O];
  else if (i < QWR_O) v = exp_Wi[i - EWI_O];
  else if (i < QWI_O) v = q_Wr[i - QWR_O];
  else if (i < KWR_O) v = q_Wi[i - QWI_O];
  else if (i < KWI_O) v = k_Wr[i - KWR_O];
  else if (i < VWR_O) v = k_Wi[i - KWI_O];
  else if (i < VWI_O) v = v_Wr[i - VWR_O];
  else if (i < CTX_O) v = v_Wi[i - VWI_O];
  else if (i < RES_O) v = ctx_W[i - CTX_O];
  else                v = res_W[i - RES_O];
  ushort_t h = f2bf(v);
  whi[i] = h;
  wlo[i] = f2bf(v - bf2f(h));
}

// ============ prep v3: MFMA everywhere, 4 waves/block, wave = col-tile ============
__global__ __launch_bounds__(256, 4) void prep_kernel(
    const float* __restrict__ z_real, const float* __restrict__ z_imag,
    const ushort_t* __restrict__ whi, const ushort_t* __restrict__ wlo,
    const float* __restrict__ gate_b,
    const float* __restrict__ ln_scale, const float* __restrict__ ln_shift,
    const float* __restrict__ mod_bias,
    const float* __restrict__ ctx_b, const float* __restrict__ res_b,
    ushort_t* __restrict__ qf, ushort_t* __restrict__ kf, ushort_t* __restrict__ vt,
    float* __restrict__ resb)
{
  const int tid  = threadIdx.x;
  const int lane = tid & 63;
  const int w    = tid >> 6;         // wave = output col-tile
  const int g    = lane >> 4;        // 0..3
  const int c    = lane & 15;        // 0..15
  const int row0 = blockIdx.x * 16;
  const int col  = w * 16 + c;       // this lane's output column
  const f32x4 z4 = {0.f, 0.f, 0.f, 0.f};

  __shared__ ushort_t s_xh[16][136];   // zf hi
  __shared__ ushort_t s_xl[16][136];   // zf lo
  __shared__ ushort_t s_a [16][136];   // post LN+ModReLU (bf16)
  __shared__ ushort_t s_tv[128][20];   // V^T staging
  __shared__ float    s_red[4][16][2]; // per-wave LN partials (sx, sxx)

  // ---- stage zf hi/lo (256 threads: row = tid>>4, col-octet = tid&15) ----
  {
    int rowl = tid >> 4;
    int col0 = (tid & 15) * 8;
    const float* src = (col0 < 64) ? (z_real + (size_t)(row0 + rowl) * 64 + col0)
                                   : (z_imag + (size_t)(row0 + rowl) * 64 + (col0 - 64));
    float4 a = *reinterpret_cast<const float4*>(src);
    float4 b = *reinterpret_cast<const float4*>(src + 4);
    float f[8] = {a.x, a.y, a.z, a.w, b.x, b.y, b.z, b.w};
    uint_t hp[4], lp[4];
    #pragma unroll
    for (int e = 0; e < 4; ++e){
      ushort_t h0 = f2bf(f[2*e]), h1 = f2bf(f[2*e+1]);
      hp[e] = (uint_t)h0 | ((uint_t)h1 << 16);
      lp[e] = (uint_t)f2bf(f[2*e]   - bf2f(h0)) |
              ((uint_t)f2bf(f[2*e+1] - bf2f(h1)) << 16);
    }
    uint4 uh; uh.x = hp[0]; uh.y = hp[1]; uh.z = hp[2]; uh.w = hp[3];
    uint4 ul; ul.x = lp[0]; ul.y = lp[1]; ul.z = lp[2]; ul.w = lp[3];
    *reinterpret_cast<uint4*>(&s_xh[rowl][col0]) = uh;
    *reinterpret_cast<uint4*>(&s_xl[rowl][col0]) = ul;
  }
  __syncthreads();

  // x fragments (zf), K=128
  short8 xh[4], xl[4];
  #pragma unroll
  for (int ks = 0; ks < 4; ++ks){
    xh[ks] = ld8(&s_xh[c][ks * 32 + g * 8]);
    xl[ks] = ld8(&s_xl[c][ks * 32 + g * 8]);
  }

  // ---- gate (compensated; all waves redundantly) ----
  float gwv[4];
  {
    f32x4 ga = z4;
    #pragma unroll
    for (int ks = 0; ks < 4; ++ks){
      int off = GATE_O + (c & 3) * 128 + ks * 32 + g * 8;
      short8 wh = ld8(whi + off), wl = ld8(wlo + off);
      ga = MFMA(xh[ks], wh, ga);
      ga = MFMA(xl[ks], wh, ga);
      ga = MFMA(xh[ks], wl, ga);
    }
    float gb = gate_b[c & 3];
    #pragma unroll
    for (int r = 0; r < 4; ++r){
      float le = ga[r] + gb;
      float mx = fmaxf(le, __shfl_xor(le, 1, 64));
      mx = fmaxf(mx, __shfl_xor(mx, 2, 64));
      float ev = __expf(le - mx);
      float sm = ev + __shfl_xor(ev, 1, 64);
      sm += __shfl_xor(sm, 2, 64);
      gwv[r] = ev / sm;
    }
  }

  // ---- MoE (compensated), this wave's col tile only ----
  f32x4 mrr = z4, mri = z4;
  #pragma unroll
  for (int e = 0; e < 4; ++e){
    float gwr[4];
    #pragma unroll
    for (int r = 0; r < 4; ++r) gwr[r] = __shfl(gwv[r], g * 16 + e, 64);
    f32x4 er = z4, ei = z4;
    #pragma unroll
    for (int ks = 0; ks < 2; ++ks){
      int boff = e * 4096 + col * 64 + ks * 32 + g * 8;
      short8 wrh = ld8(whi + EWR_O + boff);
      short8 wrl = ld8(wlo + EWR_O + boff);
      short8 wih = ld8(whi + EWI_O + boff);
      short8 wil = ld8(wlo + EWI_O + boff);
      short8 wihn = neg8(wih), wiln = neg8(wil);
      er = MFMA(xh[ks],   wrh, er);   ei = MFMA(xh[ks+2], wrh, ei);
      er = MFMA(xl[ks],   wrh, er);   ei = MFMA(xl[ks+2], wrh, ei);
      er = MFMA(xh[ks],   wrl, er);   ei = MFMA(xh[ks+2], wrl, ei);
      er = MFMA(xh[ks+2], wihn, er);  ei = MFMA(xh[ks],   wih, ei);
      er = MFMA(xl[ks+2], wihn, er);  ei = MFMA(xl[ks],   wih, ei);
      er = MFMA(xh[ks+2], wiln, er);  ei = MFMA(xh[ks],   wil, ei);
    }
    #pragma unroll
    for (int r = 0; r < 4; ++r){
      mrr[r] = fmaf(gwr[r], er[r], mrr[r]);
      mri[r] = fmaf(gwr[r], ei[r], mri[r]);
    }
  }

  // ---- ComplexLayerNorm (ddof=1, one-pass stats, cross-wave) + ModReLU ----
  {
    float hh[4], mg[4];
    #pragma unroll
    for (int r = 0; r < 4; ++r){
      hh[r] = sqrtf(mrr[r] * mrr[r] + mri[r] * mri[r]);
      mg[r] = hh[r] + EPS_F;
    }
    #pragma unroll
    for (int r = 0; r < 4; ++r){
      float sx  = qsum16(mg[r]);
      float sxx = qsum16(mg[r] * mg[r]);
      if (c == 0){ s_red[w][g * 4 + r][0] = sx; s_red[w][g * 4 + r][1] = sxx; }
    }
    __syncthreads();
    float lsc = ln_scale[col], lsh = ln_shift[col], mb = mod_bias[col];
    #pragma unroll
    for (int r = 0; r < 4; ++r){
      int rr = g * 4 + r;
      float SX  = s_red[0][rr][0] + s_red[1][rr][0] + s_red[2][rr][0] + s_red[3][rr][0];
      float SXX = s_red[0][rr][1] + s_red[1][rr][1] + s_red[2][rr][1] + s_red[3][rr][1];
      float mean = SX * (1.0f / 64.0f);
      float var  = (SXX - SX * mean) * (1.0f / 63.0f);
      float istd = rsqrtf(var + EPS_F);
      float nm = (mg[r] - mean) * istd * lsc + lsh;
      float lr, li;
      if (hh[r] > 0.f){ float ih = 1.0f / hh[r]; lr = nm * mrr[r] * ih; li = nm * mri[r] * ih; }
      else            { lr = nm; li = 0.f; }
      float nrm = sqrtf(lr * lr + li * li) + EPS_F;
      float sf  = fmaxf(nrm + mb, 0.f) / nrm;
      s_a[rr][col]      = f2bf(lr * sf);
      s_a[rr][64 + col] = f2bf(li * sf);
    }
  }
  __syncthreads();

  // ---- ctx gate (hi only): ct8 in {w, w+4} ----
  f32x4 cwa[2];
  #pragma unroll
  for (int ii = 0; ii < 2; ++ii){
    int ct8 = w + ii * 4;
    f32x4 a = z4;
    #pragma unroll
    for (int ks = 0; ks < 4; ++ks)
      a = MFMA(xh[ks], ld8(whi + CTX_O + (ct8 * 16 + c) * 128 + ks * 32 + g * 8), a);
    float cb = ctx_b[ct8 * 16 + c];
    #pragma unroll
    for (int r = 0; r < 4; ++r) cwa[ii][r] = 1.0f / (1.0f + __expf(-(a[r] + cb)));
  }

  // ---- residual (hi only): resb = 0.1*(zf @ res_W^T + b) ----
  #pragma unroll
  for (int ii = 0; ii < 2; ++ii){
    int ct8 = w + ii * 4;
    f32x4 a = z4;
    #pragma unroll
    for (int ks = 0; ks < 4; ++ks)
      a = MFMA(xh[ks], ld8(whi + RES_O + (ct8 * 16 + c) * 128 + ks * 32 + g * 8), a);
    float rb = res_b[ct8 * 16 + c];
    #pragma unroll
    for (int r = 0; r < 4; ++r)
      resb[(size_t)(row0 + 4 * g + r) * 128 + ct8 * 16 + c] = 0.1f * (a[r] + rb);
  }

  // ---- QKV (a single bf16, W compensated), this wave's col tile ----
  short8 ar_[2], ai_[2], ain_[2];
  #pragma unroll
  for (int ks = 0; ks < 2; ++ks){
    ar_[ks]  = ld8(&s_a[c][ks * 32 + g * 8]);
    ai_[ks]  = ld8(&s_a[c][64 + ks * 32 + g * 8]);
    ain_[ks] = neg8(ai_[ks]);
  }

  #pragma unroll
  for (int mat = 0; mat < 3; ++mat){
    int roff = (mat == 0) ? QWR_O : (mat == 1) ? KWR_O : VWR_O;
    int ioff = (mat == 0) ? QWI_O : (mat == 1) ? KWI_O : VWI_O;
    f32x4 orr = z4, oii = z4;
    #pragma unroll
    for (int ks = 0; ks < 2; ++ks){
      int boff = col * 64 + ks * 32 + g * 8;
      short8 wrh = ld8(whi + roff + boff);
      short8 wrl = ld8(wlo + roff + boff);
      short8 wih = ld8(whi + ioff + boff);
      short8 wil = ld8(wlo + ioff + boff);
      orr = MFMA(ar_[ks],  wrh, orr);  oii = MFMA(ai_[ks], wrh, oii);
      orr = MFMA(ar_[ks],  wrl, orr);  oii = MFMA(ai_[ks], wrl, oii);
      orr = MFMA(ain_[ks], wih, orr);  oii = MFMA(ar_[ks], wih, oii);
      orr = MFMA(ain_[ks], wil, orr);  oii = MFMA(ar_[ks], wil, oii);
    }
    if (mat == 0){
      #pragma unroll
      for (int r = 0; r < 4; ++r){
        size_t row = row0 + 4 * g + r;
        qf[row * 128 + col]      = f2bf(orr[r] * cwa[0][r] * QSC);
        qf[row * 128 + 64 + col] = f2bf(oii[r] * cwa[1][r] * QSC);
      }
    } else if (mat == 1){
      #pragma unroll
      for (int r = 0; r < 4; ++r){
        size_t row = row0 + 4 * g + r;
        kf[row * 128 + col]      = f2bf(orr[r]);
        kf[row * 128 + 64 + col] = f2bf(oii[r]);
      }
    } else {
      #pragma unroll
      for (int r = 0; r < 4; ++r){
        s_tv[col][4 * g + r]      = f2bf(orr[r]);
        s_tv[64 + col][4 * g + r] = f2bf(oii[r]);
      }
    }
  }
  __syncthreads();

  // ---- V^T write-out (256 threads) ----
  {
    int d = tid >> 1, half = tid & 1;
    uint2 t0 = *reinterpret_cast<const uint2*>(&s_tv[d][half * 8]);
    uint2 t1 = *reinterpret_cast<const uint2*>(&s_tv[d][half * 8 + 4]);
    uint4 o; o.x = t0.x; o.y = t0.y; o.z = t1.x; o.w = t1.y;
    *reinterpret_cast<uint4*>(vt + (size_t)d * 8192 + row0 + half * 8) = o;
  }
}

// ---- MFMA flash attention (swapped operands, exp2 domain, defer-max) ----
__global__ __launch_bounds__(256, 4) void attn_mfma(
    const ushort_t* __restrict__ qf, const ushort_t* __restrict__ kf, const ushort_t* __restrict__ vt,
    ushort_t* __restrict__ pacc, float* __restrict__ pm, float* __restrict__ pl)
{
  const int tid  = threadIdx.x;
  const int lane = tid & 63;
  const int w    = tid >> 6;
  const int g    = lane >> 4;
  const int hl   = lane & 15;
  const int qb   = blockIdx.x & 127;
  const int jc   = blockIdx.x >> 7;
  const int q0   = qb * 64;
  const int qr   = q0 + w * 16 + hl;

  __shared__ ushort_t s_k[32][136];
  __shared__ ushort_t s_vt[128][40];
  __shared__ uint_t   s_p32[4][16][20];

  const int kjj0 = tid >> 4;
  const int kkk  = (tid & 15) * 8;
  const int vd0  = tid >> 2;
  const int vjo  = (tid & 3) * 8;

  short8 qfrag[4];
  #pragma unroll
  for (int kt = 0; kt < 4; ++kt)
    qfrag[kt] = *reinterpret_cast<const short8*>(qf + (size_t)qr * 128 + kt * 32 + g * 8);

  f32x4 oacc[8];
  #pragma unroll
  for (int dt = 0; dt < 8; ++dt) oacc[dt] = (f32x4){0.f, 0.f, 0.f, 0.f};
  float mrun = -3.0e38f, lrun = 0.f;

  const int jstart = jc * CHUNK;

  for (int t = 0; t < TILES; ++t){
    const int jb = jstart + t * 32;
    __syncthreads();
    #pragma unroll
    for (int i = 0; i < 2; ++i){
      *reinterpret_cast<uint4*>(&s_k[kjj0 + i * 16][kkk]) =
          *reinterpret_cast<const uint4*>(kf + (size_t)(jb + kjj0 + i * 16) * 128 + kkk);
      *reinterpret_cast<uint4*>(&s_vt[vd0 + i * 64][vjo]) =
          *reinterpret_cast<const uint4*>(vt + (size_t)(vd0 + i * 64) * 8192 + jb + vjo);
    }
    __syncthreads();

    f32x4 sacc[2];
    #pragma unroll
    for (int jt = 0; jt < 2; ++jt){
      sacc[jt] = (f32x4){0.f, 0.f, 0.f, 0.f};
      #pragma unroll
      for (int kt = 0; kt < 4; ++kt){
        short8 kfr = *reinterpret_cast<const short8*>(&s_k[jt * 16 + hl][kt * 32 + g * 8]);
        sacc[jt] = __builtin_amdgcn_mfma_f32_16x16x32_bf16(kfr, qfrag[kt], sacc[jt], 0, 0, 0);
      }
    }

    float t0 = fmaxf(fmaxf(fmaxf(sacc[0][0], sacc[0][1]), fmaxf(sacc[0][2], sacc[0][3])),
                     fmaxf(fmaxf(sacc[1][0], sacc[1][1]), fmaxf(sacc[1][2], sacc[1][3])));
    t0 = fmaxf(t0, __shfl_xor(t0, 16, 64));
    t0 = fmaxf(t0, __shfl_xor(t0, 32, 64));
    if (__any(t0 > mrun)){
      float mnew = fmaxf(mrun, t0);
      float fac  = exp2f(mrun - mnew);
      lrun *= fac;
      #pragma unroll
      for (int dt = 0; dt < 8; ++dt){
        oacc[dt][0] *= fac; oacc[dt][1] *= fac; oacc[dt][2] *= fac; oacc[dt][3] *= fac;
      }
      mrun = mnew;
    }
    float pe[2][4];
    float ps = 0.f;
    #pragma unroll
    for (int jt = 0; jt < 2; ++jt)
      #pragma unroll
      for (int r = 0; r < 4; ++r){
        float p = exp2f(sacc[jt][r] - mrun);
        pe[jt][r] = p;
        ps += p;
      }
    ps += __shfl_xor(ps, 16, 64);
    ps += __shfl_xor(ps, 32, 64);
    lrun += ps;

    {
      uint2 w0; w0.x = pack2bf(pe[0][0], pe[0][1]); w0.y = pack2bf(pe[0][2], pe[0][3]);
      uint2 w1; w1.x = pack2bf(pe[1][0], pe[1][1]); w1.y = pack2bf(pe[1][2], pe[1][3]);
      *reinterpret_cast<uint2*>(&s_p32[w][hl][2 * g])     = w0;
      *reinterpret_cast<uint2*>(&s_p32[w][hl][8 + 2 * g]) = w1;
    }
    short8 pfrag = *reinterpret_cast<const short8*>(&s_p32[w][hl][4 * g]);

    #pragma unroll
    for (int dt = 0; dt < 8; ++dt){
      short8 vfr = *reinterpret_cast<const short8*>(&s_vt[dt * 16 + hl][g * 8]);
      oacc[dt] = __builtin_amdgcn_mfma_f32_16x16x32_bf16(vfr, pfrag, oacc[dt], 0, 0, 0);
    }
  }

  #pragma unroll
  for (int dt = 0; dt < 8; ++dt){
    uint2 o;
    o.x = pack2bf(oacc[dt][0], oacc[dt][1]);
    o.y = pack2bf(oacc[dt][2], oacc[dt][3]);
    *reinterpret_cast<uint2*>(pacc + ((size_t)jc * 8192 + qr) * 128 + dt * 16 + 4 * g) = o;
  }
  if (g == 0){
    pm[jc * 8192 + qr] = mrun;
    pl[jc * 8192 + qr] = lrun;
  }
}

// ---- combine chunk partials + residual + halt/stack heads ----
__global__ __launch_bounds__(256, 1) void combine_kernel(
    const ushort_t* __restrict__ pacc, const float* __restrict__ pm, const float* __restrict__ pl,
    const float* __restrict__ resb,
    const float* __restrict__ halt_W, const float* __restrict__ halt_b,
    const float* __restrict__ stack_W, const float* __restrict__ stack_b,
    float* __restrict__ out)
{
  const int tid  = threadIdx.x;
  const int lane = tid & 63;
  const int w    = tid >> 6;
  const int q    = blockIdx.x * 4 + w;

  float mv[NCH], M = -3.0e38f;
  #pragma unroll
  for (int c = 0; c < NCH; ++c){ mv[c] = pm[c * 8192 + q]; M = fmaxf(M, mv[c]); }
  float f[NCH]; float L = 0.f;
  #pragma unroll
  for (int c = 0; c < NCH; ++c){ f[c] = exp2f(mv[c] - M); L += pl[c * 8192 + q] * f[c]; }
  float invL = 1.0f / L;

  float o0 = 0.f, o1 = 0.f;
  #pragma unroll
  for (int c = 0; c < NCH; ++c){
    const ushort_t* pa = pacc + ((size_t)c * 8192 + q) * 128;
    o0 += bf2f(pa[lane])      * f[c];
    o1 += bf2f(pa[64 + lane]) * f[c];
  }
  o0 = o0 * invL + resb[(size_t)q * 128 + lane];
  o1 = o1 * invL + resb[(size_t)q * 128 + 64 + lane];
  out[(size_t)q * 64 + lane] = o0;
  out[(size_t)8192 * 64 + (size_t)q * 64 + lane] = o1;

  float ssq  = wave_sum64(o0 * o0 + o1 * o1);
  float invn = 1.0f / (sqrtf(ssq) + 1e-6f);
  float zn0 = o0 * invn, zn1 = o1 * invn;
  float hp = wave_sum64(zn0 * halt_W[lane]        + zn1 * halt_W[64 + lane]);
  float s0 = wave_sum64(zn0 * stack_W[lane]       + zn1 * stack_W[64 + lane]);
  float s1 = wave_sum64(zn0 * stack_W[128 + lane] + zn1 * stack_W[192 + lane]);
  float s2 = wave_sum64(zn0 * stack_W[256 + lane] + zn1 * stack_W[320 + lane]);
  if (lane == 0){
    out[1048576 + q] = hp + halt_b[0];
    out[1056768 + (size_t)q * 3 + 0] = s0 + stack_b[0];
    out[1056768 + (size_t)q * 3 + 1] = s1 + stack_b[1];
    out[1056768 + (size_t)q * 3 + 2] = s2 + stack_b[2];
  }
}

extern "C" void kernel_launch(void* const* d_in, const int* in_sizes, int n_in,
                              void* d_out, int out_size, void* d_ws, size_t ws_size,
                              hipStream_t stream){
  const float* z_real  = (const float*)d_in[0];
  const float* z_imag  = (const float*)d_in[1];
  const float* gate_W  = (const float*)d_in[2];
  const float* gate_b  = (const float*)d_in[3];
  const float* exp_Wr  = (const float*)d_in[4];
  const float* exp_Wi  = (const float*)d_in[5];
  const float* ln_scale= (const float*)d_in[6];
  const float* ln_shift= (const float*)d_in[7];
  const float* mod_bias= (const float*)d_in[8];
  const float* q_Wr    = (const float*)d_in[9];
  const float* q_Wi    = (const float*)d_in[10];
  const float* k_Wr    = (const float*)d_in[11];
  const float* k_Wi    = (const float*)d_in[12];
  const float* v_Wr    = (const float*)d_in[13];
  const float* v_Wi    = (const float*)d_in[14];
  const float* ctx_W   = (const float*)d_in[15];
  const float* ctx_b   = (const float*)d_in[16];
  const float* res_W   = (const float*)d_in[17];
  const float* res_b   = (const float*)d_in[18];
  const float* halt_W  = (const float*)d_in[19];
  const float* halt_b  = (const float*)d_in[20];
  const float* stack_W = (const float*)d_in[21];
  const float* stack_b = (const float*)d_in[22];

  ushort_t* qbf = (ushort_t*)d_ws;
  ushort_t* kbf = qbf + (size_t)8192*128;
  ushort_t* vtb = kbf + (size_t)8192*128;        // transposed V [128][8192]
  float* resb = (float*)(vtb + (size_t)8192*128);
  ushort_t* pacc = (ushort_t*)(resb + (size_t)8192*128);
  float* pm   = (float*)(pacc + (size_t)NCH*8192*128);
  float* pl   = pm   + NCH*8192;
  ushort_t* whi = (ushort_t*)(pl + NCH*8192);
  ushort_t* wlo = whi + WTOT;

  wconv_kernel<<<(WTOT + 255) / 256, 256, 0, stream>>>(gate_W, exp_Wr, exp_Wi,
      q_Wr, q_Wi, k_Wr, k_Wi, v_Wr, v_Wi, ctx_W, res_W, whi, wlo);
  prep_kernel<<<512, 256, 0, stream>>>(z_real, z_imag, whi, wlo, gate_b,
      ln_scale, ln_shift, mod_bias, ctx_b, res_b, qbf, kbf, vtb, resb);
  attn_mfma<<<128*NCH, 256, 0, stream>>>(qbf, kbf, vtb, pacc, pm, pl);
  combine_kernel<<<2048, 256, 0, stream>>>(pacc, pm, pl, resb,
      halt_W, halt_b, stack_W, stack_b, (float*)d_out);
}